// Round 4
// baseline (4257.966 us; speedup 1.0000x reference)
//
#include <hip/hip_runtime.h>

#define Tn 512
#define Hn 512
#define Dn 64
#define Cn 64
#define Bn 256

typedef short bf16x8 __attribute__((ext_vector_type(8)));
typedef float f32x4 __attribute__((ext_vector_type(4)));
union FragU { bf16x8 v; unsigned u[4]; };

__device__ __forceinline__ unsigned pk_bf16(float lo, float hi) {
  unsigned r;
  asm("v_cvt_pk_bf16_f32 %0, %1, %2" : "=v"(r) : "v"(lo), "v"(hi));
  return r;
}

__device__ __forceinline__ f32x4 mfma16(bf16x8 a, bf16x8 b, f32x4 c) {
  return __builtin_amdgcn_mfma_f32_16x16x32_bf16(a, b, c, 0, 0, 0);
}

// zero the flag words each launch (ws is re-poisoned to 0xAA)
__global__ void ff_init(unsigned* flags) {
  if (threadIdx.x < 512) flags[threadIdx.x] = 0u;
}

// flags spread 64B apart: index (g*2+par)*16
#define FIDX(g, par) (((g) * 2 + (par)) * 16)

// ---------------------------------------------------------------------------
// Scan: 64 blocks x 512 threads. block = (batch-group g = blk>>2) x (h-quarter
// q = blk&3): 16 batches, h rows [q*128, q*128+128). W/K/Pz/Pm fragments
// register-resident, chunk storage PERMUTED so hot-loop indices are
// compile-time: local l=0..3 = own quarter chunks, l=4..15 = partner chunks.
// Per step: [B0] x-proj + own-quarter MFMAs + x(t+1) staging (all partner-
// independent, before the poll) -> [poll, all lanes] -> [R] agent-load 3
// partner r-quarters to LDS -> sync -> [C] 24 partner MFMAs -> [U] update ->
// [W] xbuf agent store + LDS r + hidden -> sync -> tid0 release flag-add.
// ---------------------------------------------------------------------------
__global__ __launch_bounds__(512, 2) void flipflop_scan(
    const float* __restrict__ x,
    const float* __restrict__ Wm,
    const float* __restrict__ Pmat,
    const float* __restrict__ bv,
    const float* __restrict__ bz,
    const float* __restrict__ Km,
    const float* __restrict__ Pzm,
    float* __restrict__ hidden,
    unsigned* __restrict__ flags,
    unsigned long long* __restrict__ xbuf)
{
  __shared__ char lds[36864];
  char* const r_lds = lds;           // 2 x 16384 B : r(t) bf16 [b][h] dbuf, swz ^((b&7)<<4)
  char* const x_lds = lds + 32768;   // 2 x 2048 B  : x_t bf16 [b][d] dbuf

  const int tid  = threadIdx.x;
  const int lane = tid & 63;
  const int wv   = tid >> 6;        // 0..7  (wave = one 16-row m-tile)
  const int lm   = lane & 15;
  const int g4   = lane >> 4;       // 0..3
  const int blk  = blockIdx.x;
  const int g    = blk >> 2;        // batch group 0..15
  const int q    = blk & 3;         // h quarter 0..3
  const int b0   = g * 16;

  // ---- persistent weight fragments, permuted chunk order ----
  FragU wA[16], kA[16], pzA[2], pmA[2];
  float bvr[4], bzr[4];

  const int hrow = q * 128 + wv * 16 + lm;   // A-frag m row (global h)
#pragma unroll
  for (int l = 0; l < 16; ++l) {
    int gc;                                   // global chunk 0..15
    if (l < 4) gc = q * 4 + l;
    else {
      const int sel = (l - 4) >> 2, cc = (l - 4) & 3;
      gc = (sel + (sel >= q ? 1 : 0)) * 4 + cc;
    }
    float4 a0 = *(const float4*)(Wm + hrow * Hn + gc * 32 + g4 * 8);
    float4 a1 = *(const float4*)(Wm + hrow * Hn + gc * 32 + g4 * 8 + 4);
    wA[l].u[0] = pk_bf16(a0.x, a0.y); wA[l].u[1] = pk_bf16(a0.z, a0.w);
    wA[l].u[2] = pk_bf16(a1.x, a1.y); wA[l].u[3] = pk_bf16(a1.z, a1.w);
    float4 k0 = *(const float4*)(Km + hrow * Hn + gc * 32 + g4 * 8);
    float4 k1 = *(const float4*)(Km + hrow * Hn + gc * 32 + g4 * 8 + 4);
    kA[l].u[0] = pk_bf16(k0.x, k0.y); kA[l].u[1] = pk_bf16(k0.z, k0.w);
    kA[l].u[2] = pk_bf16(k1.x, k1.y); kA[l].u[3] = pk_bf16(k1.z, k1.w);
  }
#pragma unroll
  for (int c = 0; c < 2; ++c) {
    float4 p0 = *(const float4*)(Pzm + hrow * Dn + c * 32 + g4 * 8);
    float4 p1 = *(const float4*)(Pzm + hrow * Dn + c * 32 + g4 * 8 + 4);
    pzA[c].u[0] = pk_bf16(p0.x, p0.y); pzA[c].u[1] = pk_bf16(p0.z, p0.w);
    pzA[c].u[2] = pk_bf16(p1.x, p1.y); pzA[c].u[3] = pk_bf16(p1.z, p1.w);
    if (q < 2) {   // Pm nonzero only for h < 256 (= quarters 0,1)
      float4 m0 = *(const float4*)(Pmat + hrow * Dn + c * 32 + g4 * 8);
      float4 m1 = *(const float4*)(Pmat + hrow * Dn + c * 32 + g4 * 8 + 4);
      pmA[c].u[0] = pk_bf16(m0.x, m0.y); pmA[c].u[1] = pk_bf16(m0.z, m0.w);
      pmA[c].u[2] = pk_bf16(m1.x, m1.y); pmA[c].u[3] = pk_bf16(m1.z, m1.w);
    } else {
      pmA[c].u[0] = pmA[c].u[1] = pmA[c].u[2] = pmA[c].u[3] = 0u;
    }
  }
  const int hc = q * 128 + wv * 16 + g4 * 4;   // C-frag row base (global h)
#pragma unroll
  for (int i = 0; i < 4; ++i) { bvr[i] = bv[hc + i]; bzr[i] = bz[hc + i]; }

  // zero r double-buffer (r(0) = relu(0) = 0); 512 thr x 64 B = both buffers
  {
    f32x4 z4 = {0.f, 0.f, 0.f, 0.f};
#pragma unroll
    for (int i = 0; i < 4; ++i) *(f32x4*)(r_lds + tid * 64 + i * 16) = z4;
  }

  f32x4 v_ = {0.f, 0.f, 0.f, 0.f};

  // x handling: thread (xb = tid>>5, xd0 = (tid&31)*2); stage x(0) now,
  // prefetch x(1) into xreg. In-loop: step t stages x(t+1), prefetches x(t+2).
  const int xb  = tid >> 5;
  const int xd0 = (tid & 31) * 2;
  const float* xbase = x + (size_t)(b0 + xb) * Tn * Dn + xd0;
  {
    float2 x0 = *(const float2*)(xbase);
    *(unsigned*)(x_lds + ((xb * 128 + xd0 * 2) ^ ((xb & 7) << 4))) =
        pk_bf16(x0.x, x0.y);
  }
  float2 xreg = *(const float2*)(xbase + Dn);   // x(1)

  __syncthreads();

  for (int t = 0; t < Tn; ++t) {
    const int par = t & 1;
    const char* rbuf = r_lds + par * 16384;

    // ---- phase B0 (partner-independent): x-proj + own-quarter MFMAs ----
    f32x4 aw = {0.f, 0.f, 0.f, 0.f}, ak = {0.f, 0.f, 0.f, 0.f};
    {
      FragU xf0, xf1;
      xf0.v = *(const bf16x8*)(x_lds + par * 2048 +
          ((lm * 128 + g4 * 16) ^ ((lm & 7) << 4)));
      xf1.v = *(const bf16x8*)(x_lds + par * 2048 +
          ((lm * 128 + 64 + g4 * 16) ^ ((lm & 7) << 4)));
      ak = mfma16(pzA[0].v, xf0.v, ak);
      ak = mfma16(pzA[1].v, xf1.v, ak);
      if (q < 2) {
        aw = mfma16(pmA[0].v, xf0.v, aw);
        aw = mfma16(pmA[1].v, xf1.v, aw);
      }
#pragma unroll
      for (int cc = 0; cc < 4; ++cc) {
        FragU rb;
        rb.v = *(const bf16x8*)(rbuf +
            ((lm * 1024 + q * 256 + cc * 64 + g4 * 16) ^ ((lm & 7) << 4)));
        aw = mfma16(wA[cc].v, rb.v, aw);
        ak = mfma16(kA[cc].v, rb.v, ak);
      }
      // stage x(t+1) into the other x buffer; prefetch x(t+2)
      *(unsigned*)(x_lds + (par ^ 1) * 2048 +
          ((xb * 128 + xd0 * 2) ^ ((xb & 7) << 4))) = pk_bf16(xreg.x, xreg.y);
      const int tn2 = (t + 2 < Tn) ? t + 2 : Tn - 1;
      xreg = *(const float2*)(xbase + (size_t)tn2 * Dn);
    }

    // ---- poll (all lanes, same addr -> 1 req/wave) + phase R ----
    if (t > 0) {
      const unsigned tgt = 4u * (unsigned)((t + 1) >> 1);
      unsigned vfl; int sp = 0;
      do {
        vfl = __hip_atomic_load(&flags[FIDX(g, par)], __ATOMIC_RELAXED,
                                __HIP_MEMORY_SCOPE_AGENT);
      } while (vfl < tgt && ++sp < 65536);
      (void)__hip_atomic_load(&flags[FIDX(g, par)], __ATOMIC_ACQUIRE,
                              __HIP_MEMORY_SCOPE_AGENT);
#pragma unroll
      for (int j = 0; j < 3; ++j) {
        const int wg2 = tid + j * 512;           // 0..1535
        const int sel = wg2 >> 9;                // 0..2
        const int qq  = sel + (sel >= q ? 1 : 0);
        const int u   = wg2 & 511;               // ull index in quarter
        const int b   = u >> 5, hw2 = u & 31;
        unsigned long long val = __hip_atomic_load(
            xbuf + (size_t)((g * 2 + par) * 4 + qq) * 512 + u,
            __ATOMIC_RELAXED, __HIP_MEMORY_SCOPE_AGENT);
        *(unsigned long long*)(r_lds + par * 16384 +
            ((b * 1024 + qq * 256 + hw2 * 8) ^ ((b & 7) << 4))) = val;
      }
    }
    __syncthreads();

    // ---- phase C: 24 partner-chunk MFMAs (compile-time fragment indices) ----
#pragma unroll
    for (int sel = 0; sel < 3; ++sel) {
      const int qbase = (sel + (sel >= q ? 1 : 0)) * 256;
#pragma unroll
      for (int cc = 0; cc < 4; ++cc) {
        FragU rb;
        rb.v = *(const bf16x8*)(rbuf +
            ((lm * 1024 + qbase + cc * 64 + g4 * 16) ^ ((lm & 7) << 4)));
        aw = mfma16(wA[4 + sel * 4 + cc].v, rb.v, aw);
        ak = mfma16(kA[4 + sel * 4 + cc].v, rb.v, ak);
      }
    }

    // ---- phase U: z = 10*DT*sigmoid = sigmoid (10*0.1 = 1) ----
#pragma unroll
    for (int i = 0; i < 4; ++i) {
      float s  = ak[i] + bzr[i];
      float zz = 1.0f / (1.0f + __expf(-s));
      v_[i] = (1.0f - zz) * v_[i] + 0.1f * (aw[i] + bvr[i]);
    }
    const unsigned lo = pk_bf16(fmaxf(v_[0], 0.f), fmaxf(v_[1], 0.f));
    const unsigned hi = pk_bf16(fmaxf(v_[2], 0.f), fmaxf(v_[3], 0.f));

    // ---- phase W: xbuf agent store first, then LDS r, then hidden ----
    {
      if (t < Tn - 1) {
        unsigned long long val = (unsigned long long)lo | ((unsigned long long)hi << 32);
        __hip_atomic_store(
            xbuf + (size_t)((g * 2 + (par ^ 1)) * 4 + q) * 512 + lm * 32 + wv * 4 + g4,
            val, __ATOMIC_RELAXED, __HIP_MEMORY_SCOPE_AGENT);
      }
      char* wr = r_lds + (par ^ 1) * 16384;
      *(uint2*)(wr + ((lm * 1024 + q * 256 + wv * 32 + g4 * 8) ^ ((lm & 7) << 4))) =
          make_uint2(lo, hi);
      float* hp = hidden + (((size_t)(b0 + lm) * Tn + t) * Hn + q * 128 + wv * 16 + g4 * 4);
      *(f32x4*)hp = v_;
    }
    __syncthreads();   // all lanes' xbuf stores happen-before tid0's flag add
    if (t < Tn - 1 && tid == 0)
      __hip_atomic_fetch_add(&flags[FIDX(g, par ^ 1)], 1u,
                             __ATOMIC_RELEASE, __HIP_MEMORY_SCOPE_AGENT);
  }
}

// ---------------------------------------------------------------------------
// FC: out[r,:] = hidden[r,:] @ fc_w^T + fc_b over r = b*T+t. 2048 blocks x 256
// threads (4 waves); wave wv owns n-tile wv (16 cols); hidden 64-row tile
// staged bf16 in LDS; bw[16] = 64 VGPR/lane. HBM-bound (268 MB read).
// ---------------------------------------------------------------------------
__global__ __launch_bounds__(256, 2) void flipflop_fc(
    const float* __restrict__ hidden,
    const float* __restrict__ fcw,
    const float* __restrict__ fcb,
    float* __restrict__ out)
{
  __shared__ char lds[65536];
  const int tid  = threadIdx.x;
  const int lane = tid & 63;
  const int wv   = tid >> 6;   // 0..3 = n-tile
  const int lm   = lane & 15;
  const int g4   = lane >> 4;

  const float4* h4 = (const float4*)hidden + (size_t)blockIdx.x * 8192;
#pragma unroll
  for (int i = 0; i < 32; ++i) {
    const int f = i * 256 + tid;
    float4 d = h4[f];
    const int row = f >> 7, c4 = f & 127;
    *(uint2*)(lds + ((row * 1024 + c4 * 8) ^ ((row & 7) << 4))) =
        make_uint2(pk_bf16(d.x, d.y), pk_bf16(d.z, d.w));
  }

  FragU bw[16];
  const int cc = wv * 16 + lm;
#pragma unroll
  for (int kc = 0; kc < 16; ++kc) {
    float4 a0 = *(const float4*)(fcw + cc * Hn + kc * 32 + g4 * 8);
    float4 a1 = *(const float4*)(fcw + cc * Hn + kc * 32 + g4 * 8 + 4);
    bw[kc].u[0] = pk_bf16(a0.x, a0.y); bw[kc].u[1] = pk_bf16(a0.z, a0.w);
    bw[kc].u[2] = pk_bf16(a1.x, a1.y); bw[kc].u[3] = pk_bf16(a1.z, a1.w);
  }
  const float fb = fcb[cc];

  __syncthreads();

  f32x4 acc0 = {0.f,0.f,0.f,0.f}, acc1 = {0.f,0.f,0.f,0.f};
  f32x4 acc2 = {0.f,0.f,0.f,0.f}, acc3 = {0.f,0.f,0.f,0.f};
#pragma unroll
  for (int kc = 0; kc < 16; ++kc) {
    FragU a0, a1, a2, a3;
    a0.v = *(const bf16x8*)(lds + ((( 0 + lm) * 1024 + kc * 64 + g4 * 16) ^ ((lm & 7) << 4)));
    a1.v = *(const bf16x8*)(lds + (((16 + lm) * 1024 + kc * 64 + g4 * 16) ^ ((lm & 7) << 4)));
    a2.v = *(const bf16x8*)(lds + (((32 + lm) * 1024 + kc * 64 + g4 * 16) ^ ((lm & 7) << 4)));
    a3.v = *(const bf16x8*)(lds + (((48 + lm) * 1024 + kc * 64 + g4 * 16) ^ ((lm & 7) << 4)));
    acc0 = mfma16(a0.v, bw[kc].v, acc0);
    acc1 = mfma16(a1.v, bw[kc].v, acc1);
    acc2 = mfma16(a2.v, bw[kc].v, acc2);
    acc3 = mfma16(a3.v, bw[kc].v, acc3);
  }

  const size_t rbase = (size_t)blockIdx.x * 64;
#pragma unroll
  for (int i = 0; i < 4; ++i) {
    out[(rbase +  0 + g4 * 4 + i) * Cn + cc] = acc0[i] + fb;
    out[(rbase + 16 + g4 * 4 + i) * Cn + cc] = acc1[i] + fb;
    out[(rbase + 32 + g4 * 4 + i) * Cn + cc] = acc2[i] + fb;
    out[(rbase + 48 + g4 * 4 + i) * Cn + cc] = acc3[i] + fb;
  }
}

extern "C" void kernel_launch(void* const* d_in, const int* in_sizes, int n_in,
                              void* d_out, int out_size, void* d_ws, size_t ws_size,
                              hipStream_t stream) {
  (void)in_sizes; (void)n_in; (void)out_size; (void)ws_size;
  const float* x   = (const float*)d_in[0];
  const float* Wm  = (const float*)d_in[1];
  const float* P   = (const float*)d_in[2];
  const float* bv  = (const float*)d_in[3];
  const float* bz  = (const float*)d_in[4];
  const float* Km  = (const float*)d_in[5];
  const float* Pz  = (const float*)d_in[6];
  const float* fcw = (const float*)d_in[7];
  const float* fcb = (const float*)d_in[8];

  float* out    = (float*)d_out;
  float* hidden = out + (size_t)Bn * Tn * Cn;   // outputs concat: out | hidden

  unsigned* flags = (unsigned*)d_ws;                                    // 2 KB
  unsigned long long* xbuf = (unsigned long long*)((char*)d_ws + 2048); // 512 KB

  ff_init<<<dim3(1), dim3(512), 0, stream>>>(flags);
  flipflop_scan<<<dim3(64), dim3(512), 0, stream>>>(x, Wm, P, bv, bz, Km, Pz,
                                                    hidden, flags, xbuf);
  flipflop_fc<<<dim3(2048), dim3(256), 0, stream>>>(hidden, fcw, fcb, out);
}

// Round 6
// 3990.061 us; speedup vs baseline: 1.0671x; 1.0671x over previous
//
#include <hip/hip_runtime.h>

#define Tn 512
#define Hn 512
#define Dn 64
#define Cn 64
#define Bn 256

typedef short bf16x8 __attribute__((ext_vector_type(8)));
typedef float f32x4 __attribute__((ext_vector_type(4)));
union FragU { bf16x8 v; unsigned u[4]; };

__device__ __forceinline__ unsigned pk_bf16(float lo, float hi) {
  unsigned r;
  asm("v_cvt_pk_bf16_f32 %0, %1, %2" : "=v"(r) : "v"(lo), "v"(hi));
  return r;
}

__device__ __forceinline__ f32x4 mfma16(bf16x8 a, bf16x8 b, f32x4 c) {
  return __builtin_amdgcn_mfma_f32_16x16x32_bf16(a, b, c, 0, 0, 0);
}

// zero the flag words each launch (ws is re-poisoned to 0xAA)
__global__ void ff_init(unsigned* flags) {
  if (threadIdx.x < 512) flags[threadIdx.x] = 0u;
}

// flags spread 64B apart: index (g*2+par)*16
#define FIDX(g, par) (((g) * 2 + (par)) * 16)

// ---------------------------------------------------------------------------
// Scan: 64 blocks x 512 threads, ONE block/CU. amdgpu_waves_per_eu(2,2) pins
// 2 waves/EU -> 256-VGPR budget so the ~144 fragment VGPRs stay resident
// (R4's VGPR_Count=124 showed a 128-reg budget + spills -> 3.9 ms).
// block = (batch-group g = blk>>2) x (h-quarter q = blk&3): 16 batches,
// h rows [q*128, q*128+128). Chunk storage PERMUTED: l=0..3 own quarter,
// l=4..15 partners, all hot-loop indices compile-time.
// Per step: [B0] x-proj + own-quarter MFMAs + x(t+1) staging (partner-
// independent, before the poll) -> [poll, all lanes] -> [R] 3 agent loads ->
// 3 LDS writes -> sync -> [C] 24 partner MFMAs -> [U] update -> [W] xbuf
// agent store + LDS r + hidden -> sync -> tid0 release flag-add.
// ---------------------------------------------------------------------------
__global__ __attribute__((amdgpu_flat_work_group_size(512, 512),
                          amdgpu_waves_per_eu(2, 2)))
void flipflop_scan(
    const float* __restrict__ x,
    const float* __restrict__ Wm,
    const float* __restrict__ Pmat,
    const float* __restrict__ bv,
    const float* __restrict__ bz,
    const float* __restrict__ Km,
    const float* __restrict__ Pzm,
    float* __restrict__ hidden,
    unsigned* __restrict__ flags,
    unsigned long long* __restrict__ xbuf)
{
  __shared__ char lds[36864];
  char* const r_lds = lds;           // 2 x 16384 B : r(t) bf16 [b][h] dbuf, swz ^((b&7)<<4)
  char* const x_lds = lds + 32768;   // 2 x 2048 B  : x_t bf16 [b][d] dbuf

  const int tid  = threadIdx.x;
  const int lane = tid & 63;
  const int wv   = tid >> 6;        // 0..7  (wave = one 16-row m-tile)
  const int lm   = lane & 15;
  const int g4   = lane >> 4;       // 0..3
  const int blk  = blockIdx.x;
  const int g    = blk >> 2;        // batch group 0..15
  const int q    = blk & 3;         // h quarter 0..3
  const int b0   = g * 16;

  // ---- persistent weight fragments, permuted chunk order ----
  FragU wA[16], kA[16], pzA[2], pmA[2];
  float bvr[4], bzr[4];

  const int hrow = q * 128 + wv * 16 + lm;   // A-frag m row (global h)
#pragma unroll
  for (int l = 0; l < 16; ++l) {
    int gc;                                   // global chunk 0..15
    if (l < 4) gc = q * 4 + l;
    else {
      const int sel = (l - 4) >> 2, cc = (l - 4) & 3;
      gc = (sel + (sel >= q ? 1 : 0)) * 4 + cc;
    }
    float4 a0 = *(const float4*)(Wm + hrow * Hn + gc * 32 + g4 * 8);
    float4 a1 = *(const float4*)(Wm + hrow * Hn + gc * 32 + g4 * 8 + 4);
    wA[l].u[0] = pk_bf16(a0.x, a0.y); wA[l].u[1] = pk_bf16(a0.z, a0.w);
    wA[l].u[2] = pk_bf16(a1.x, a1.y); wA[l].u[3] = pk_bf16(a1.z, a1.w);
    float4 k0 = *(const float4*)(Km + hrow * Hn + gc * 32 + g4 * 8);
    float4 k1 = *(const float4*)(Km + hrow * Hn + gc * 32 + g4 * 8 + 4);
    kA[l].u[0] = pk_bf16(k0.x, k0.y); kA[l].u[1] = pk_bf16(k0.z, k0.w);
    kA[l].u[2] = pk_bf16(k1.x, k1.y); kA[l].u[3] = pk_bf16(k1.z, k1.w);
  }
#pragma unroll
  for (int c = 0; c < 2; ++c) {
    float4 p0 = *(const float4*)(Pzm + hrow * Dn + c * 32 + g4 * 8);
    float4 p1 = *(const float4*)(Pzm + hrow * Dn + c * 32 + g4 * 8 + 4);
    pzA[c].u[0] = pk_bf16(p0.x, p0.y); pzA[c].u[1] = pk_bf16(p0.z, p0.w);
    pzA[c].u[2] = pk_bf16(p1.x, p1.y); pzA[c].u[3] = pk_bf16(p1.z, p1.w);
    if (q < 2) {   // Pm nonzero only for h < 256 (= quarters 0,1)
      float4 m0 = *(const float4*)(Pmat + hrow * Dn + c * 32 + g4 * 8);
      float4 m1 = *(const float4*)(Pmat + hrow * Dn + c * 32 + g4 * 8 + 4);
      pmA[c].u[0] = pk_bf16(m0.x, m0.y); pmA[c].u[1] = pk_bf16(m0.z, m0.w);
      pmA[c].u[2] = pk_bf16(m1.x, m1.y); pmA[c].u[3] = pk_bf16(m1.z, m1.w);
    } else {
      pmA[c].u[0] = pmA[c].u[1] = pmA[c].u[2] = pmA[c].u[3] = 0u;
    }
  }
  const int hc = q * 128 + wv * 16 + g4 * 4;   // C-frag row base (global h)
#pragma unroll
  for (int i = 0; i < 4; ++i) { bvr[i] = bv[hc + i]; bzr[i] = bz[hc + i]; }

  // zero r double-buffer (r(0) = relu(0) = 0); 512 thr x 64 B = both buffers
  {
    f32x4 z4 = {0.f, 0.f, 0.f, 0.f};
#pragma unroll
    for (int i = 0; i < 4; ++i) *(f32x4*)(r_lds + tid * 64 + i * 16) = z4;
  }

  f32x4 v_ = {0.f, 0.f, 0.f, 0.f};

  // x handling: thread (xb = tid>>5, xd0 = (tid&31)*2); stage x(0) now,
  // prefetch x(1). In-loop: step t stages x(t+1), prefetches x(t+2).
  const int xb  = tid >> 5;
  const int xd0 = (tid & 31) * 2;
  const float* xbase = x + (size_t)(b0 + xb) * Tn * Dn + xd0;
  {
    float2 x0 = *(const float2*)(xbase);
    *(unsigned*)(x_lds + ((xb * 128 + xd0 * 2) ^ ((xb & 7) << 4))) =
        pk_bf16(x0.x, x0.y);
  }
  float2 xreg = *(const float2*)(xbase + Dn);   // x(1)

  __syncthreads();

  for (int t = 0; t < Tn; ++t) {
    const int par = t & 1;
    const char* rbuf = r_lds + par * 16384;

    // ---- phase B0 (partner-independent): x-proj + own-quarter MFMAs ----
    f32x4 aw = {0.f, 0.f, 0.f, 0.f}, ak = {0.f, 0.f, 0.f, 0.f};
    {
      FragU xf0, xf1;
      xf0.v = *(const bf16x8*)(x_lds + par * 2048 +
          ((lm * 128 + g4 * 16) ^ ((lm & 7) << 4)));
      xf1.v = *(const bf16x8*)(x_lds + par * 2048 +
          ((lm * 128 + 64 + g4 * 16) ^ ((lm & 7) << 4)));
      ak = mfma16(pzA[0].v, xf0.v, ak);
      ak = mfma16(pzA[1].v, xf1.v, ak);
      if (q < 2) {
        aw = mfma16(pmA[0].v, xf0.v, aw);
        aw = mfma16(pmA[1].v, xf1.v, aw);
      }
#pragma unroll
      for (int cc = 0; cc < 4; ++cc) {
        FragU rb;
        rb.v = *(const bf16x8*)(rbuf +
            ((lm * 1024 + q * 256 + cc * 64 + g4 * 16) ^ ((lm & 7) << 4)));
        aw = mfma16(wA[cc].v, rb.v, aw);
        ak = mfma16(kA[cc].v, rb.v, ak);
      }
      // stage x(t+1) into the other x buffer; prefetch x(t+2)
      *(unsigned*)(x_lds + (par ^ 1) * 2048 +
          ((xb * 128 + xd0 * 2) ^ ((xb & 7) << 4))) = pk_bf16(xreg.x, xreg.y);
      const int tn2 = (t + 2 < Tn) ? t + 2 : Tn - 1;
      xreg = *(const float2*)(xbase + (size_t)tn2 * Dn);
    }

    // ---- poll (all lanes, same addr -> 1 req/wave) + phase R ----
    if (t > 0) {
      const unsigned tgt = 4u * (unsigned)((t + 1) >> 1);
      unsigned vfl; int sp = 0;
      do {
        vfl = __hip_atomic_load(&flags[FIDX(g, par)], __ATOMIC_RELAXED,
                                __HIP_MEMORY_SCOPE_AGENT);
      } while (vfl < tgt && ++sp < 65536);
      (void)__hip_atomic_load(&flags[FIDX(g, par)], __ATOMIC_ACQUIRE,
                              __HIP_MEMORY_SCOPE_AGENT);
      // 3 agent loads first, then 3 LDS writes. q*256 (bits 8-9) is disjoint
      // from the XOR swizzle (bits 4-6), hw2*8 (bits 3-7), b*1024 (bits 10+),
      // so swz + q*256 == canonical ((b*1024 + q*256 + hw2*8) ^ ((b&7)<<4)).
      const int b   = tid >> 5, hw2 = tid & 31;
      const int q0  = (q == 0) ? 1 : 0;
      const int q1  = (q <= 1) ? 2 : 1;
      const int q2  = (q <= 2) ? 3 : 2;
      const size_t base = (size_t)((g * 2 + par) * 4) * 512 + tid;
      unsigned long long v0 = __hip_atomic_load(
          xbuf + base + (size_t)(q0 - 0) * 512 - tid + (size_t)q0 * 512 + tid - (size_t)q0 * 512,
          __ATOMIC_RELAXED, __HIP_MEMORY_SCOPE_AGENT);
      v0 = __hip_atomic_load(xbuf + base + (size_t)q0 * 512,
                             __ATOMIC_RELAXED, __HIP_MEMORY_SCOPE_AGENT);
      unsigned long long v1 = __hip_atomic_load(xbuf + base + (size_t)q1 * 512,
                             __ATOMIC_RELAXED, __HIP_MEMORY_SCOPE_AGENT);
      unsigned long long v2 = __hip_atomic_load(xbuf + base + (size_t)q2 * 512,
                             __ATOMIC_RELAXED, __HIP_MEMORY_SCOPE_AGENT);
      char* const dst = r_lds + par * 16384;
      const int swz = (b * 1024 + hw2 * 8) ^ ((b & 7) << 4);
      *(unsigned long long*)(dst + swz + q0 * 256) = v0;
      *(unsigned long long*)(dst + swz + q1 * 256) = v1;
      *(unsigned long long*)(dst + swz + q2 * 256) = v2;
    }
    __syncthreads();

    // ---- phase C: 24 partner-chunk MFMAs (compile-time fragment indices) ----
#pragma unroll
    for (int sel = 0; sel < 3; ++sel) {
      const int qbase = (sel + (sel >= q ? 1 : 0)) * 256;
#pragma unroll
      for (int cc = 0; cc < 4; ++cc) {
        FragU rb;
        rb.v = *(const bf16x8*)(rbuf +
            ((lm * 1024 + qbase + cc * 64 + g4 * 16) ^ ((lm & 7) << 4)));
        aw = mfma16(wA[4 + sel * 4 + cc].v, rb.v, aw);
        ak = mfma16(kA[4 + sel * 4 + cc].v, rb.v, ak);
      }
    }

    // ---- phase U: z = 10*DT*sigmoid = sigmoid (10*0.1 = 1) ----
#pragma unroll
    for (int i = 0; i < 4; ++i) {
      float s  = ak[i] + bzr[i];
      float zz = 1.0f / (1.0f + __expf(-s));
      v_[i] = (1.0f - zz) * v_[i] + 0.1f * (aw[i] + bvr[i]);
    }
    const unsigned lo = pk_bf16(fmaxf(v_[0], 0.f), fmaxf(v_[1], 0.f));
    const unsigned hi = pk_bf16(fmaxf(v_[2], 0.f), fmaxf(v_[3], 0.f));

    // ---- phase W: xbuf agent store first, then LDS r, then hidden ----
    {
      if (t < Tn - 1) {
        unsigned long long val = (unsigned long long)lo | ((unsigned long long)hi << 32);
        __hip_atomic_store(
            xbuf + (size_t)((g * 2 + (par ^ 1)) * 4 + q) * 512 + lm * 32 + wv * 4 + g4,
            val, __ATOMIC_RELAXED, __HIP_MEMORY_SCOPE_AGENT);
      }
      char* wr = r_lds + (par ^ 1) * 16384;
      *(uint2*)(wr + ((lm * 1024 + q * 256 + wv * 32 + g4 * 8) ^ ((lm & 7) << 4))) =
          make_uint2(lo, hi);
      float* hp = hidden + (((size_t)(b0 + lm) * Tn + t) * Hn + q * 128 + wv * 16 + g4 * 4);
      *(f32x4*)hp = v_;
    }
    __syncthreads();   // all lanes' xbuf stores happen-before tid0's flag add
    if (t < Tn - 1 && tid == 0)
      __hip_atomic_fetch_add(&flags[FIDX(g, par ^ 1)], 1u,
                             __ATOMIC_RELEASE, __HIP_MEMORY_SCOPE_AGENT);
  }
}

// ---------------------------------------------------------------------------
// FC: out[r,:] = hidden[r,:] @ fc_w^T + fc_b over r = b*T+t. 4096 blocks x 256
// threads, 32 rows/block, 32 KB LDS -> 4 blocks/CU (16 waves/CU) for HBM
// latency hiding. Wave wv owns n-tile wv (16 cols) over both 16-row m-tiles.
// ---------------------------------------------------------------------------
__global__ __launch_bounds__(256, 4) void flipflop_fc(
    const float* __restrict__ hidden,
    const float* __restrict__ fcw,
    const float* __restrict__ fcb,
    float* __restrict__ out)
{
  __shared__ char lds[32768];
  const int tid  = threadIdx.x;
  const int lane = tid & 63;
  const int wv   = tid >> 6;   // 0..3 = n-tile
  const int lm   = lane & 15;
  const int g4   = lane >> 4;

  const float4* h4 = (const float4*)hidden + (size_t)blockIdx.x * 4096;
#pragma unroll
  for (int i = 0; i < 16; ++i) {
    const int f = i * 256 + tid;
    float4 d = h4[f];
    const int row = f >> 7, c4 = f & 127;
    *(uint2*)(lds + ((row * 1024 + c4 * 8) ^ ((row & 7) << 4))) =
        make_uint2(pk_bf16(d.x, d.y), pk_bf16(d.z, d.w));
  }

  FragU bw[16];
  const int cc = wv * 16 + lm;
#pragma unroll
  for (int kc = 0; kc < 16; ++kc) {
    float4 a0 = *(const float4*)(fcw + cc * Hn + kc * 32 + g4 * 8);
    float4 a1 = *(const float4*)(fcw + cc * Hn + kc * 32 + g4 * 8 + 4);
    bw[kc].u[0] = pk_bf16(a0.x, a0.y); bw[kc].u[1] = pk_bf16(a0.z, a0.w);
    bw[kc].u[2] = pk_bf16(a1.x, a1.y); bw[kc].u[3] = pk_bf16(a1.z, a1.w);
  }
  const float fb = fcb[cc];

  __syncthreads();

  f32x4 acc0 = {0.f,0.f,0.f,0.f}, acc1 = {0.f,0.f,0.f,0.f};
#pragma unroll
  for (int kc = 0; kc < 16; ++kc) {
    FragU a0, a1;
    a0.v = *(const bf16x8*)(lds + ((( 0 + lm) * 1024 + kc * 64 + g4 * 16) ^ ((lm & 7) << 4)));
    a1.v = *(const bf16x8*)(lds + (((16 + lm) * 1024 + kc * 64 + g4 * 16) ^ ((lm & 7) << 4)));
    acc0 = mfma16(a0.v, bw[kc].v, acc0);
    acc1 = mfma16(a1.v, bw[kc].v, acc1);
  }

  const size_t rbase = (size_t)blockIdx.x * 32;
#pragma unroll
  for (int i = 0; i < 4; ++i) {
    out[(rbase +  0 + g4 * 4 + i) * Cn + cc] = acc0[i] + fb;
    out[(rbase + 16 + g4 * 4 + i) * Cn + cc] = acc1[i] + fb;
  }
}

extern "C" void kernel_launch(void* const* d_in, const int* in_sizes, int n_in,
                              void* d_out, int out_size, void* d_ws, size_t ws_size,
                              hipStream_t stream) {
  (void)in_sizes; (void)n_in; (void)out_size; (void)ws_size;
  const float* x   = (const float*)d_in[0];
  const float* Wm  = (const float*)d_in[1];
  const float* P   = (const float*)d_in[2];
  const float* bv  = (const float*)d_in[3];
  const float* bz  = (const float*)d_in[4];
  const float* Km  = (const float*)d_in[5];
  const float* Pz  = (const float*)d_in[6];
  const float* fcw = (const float*)d_in[7];
  const float* fcb = (const float*)d_in[8];

  float* out    = (float*)d_out;
  float* hidden = out + (size_t)Bn * Tn * Cn;   // outputs concat: out | hidden

  unsigned* flags = (unsigned*)d_ws;                                    // 2 KB
  unsigned long long* xbuf = (unsigned long long*)((char*)d_ws + 2048); // 512 KB

  ff_init<<<dim3(1), dim3(512), 0, stream>>>(flags);
  flipflop_scan<<<dim3(64), dim3(512), 0, stream>>>(x, Wm, P, bv, bz, Km, Pz,
                                                    hidden, flags, xbuf);
  flipflop_fc<<<dim3(4096), dim3(256), 0, stream>>>(hidden, fcw, fcb, out);
}